// Round 1
// baseline (1750.702 us; speedup 1.0000x reference)
//
#include <hip/hip_runtime.h>
#include <math.h>

#define NSP 262144  // 64^3
static constexpr float TWO_PI_OVER_64 = 0.09817477042468103f;

// ---------------------------------------------------------------------------
// Lift: x[b,c,s] = lw[0,c]*vel[b,s] + lw[1,c]*ptt[b,s] + lb[c]
// ---------------------------------------------------------------------------
__global__ __launch_bounds__(256) void k_lift(const float* __restrict__ vel,
                                              const float* __restrict__ ptt,
                                              const float* __restrict__ lw,
                                              const float* __restrict__ lb,
                                              float* __restrict__ x) {
  int idx = blockIdx.x * 256 + threadIdx.x;  // over B*NSP
  int b = idx >> 18;
  int s = idx & (NSP - 1);
  float v = vel[idx];
  float p = ptt[idx];
  float* xb = x + (size_t)b * 32 * NSP + s;
#pragma unroll
  for (int c = 0; c < 32; ++c)
    xb[(size_t)c * NSP] = lw[c] * v + lw[32 + c] * p + lb[c];
}

// ---------------------------------------------------------------------------
// Forward DFT along W: x[bc,d,h,0..63] -> X1[bc,d,h,kw] kw=0..7 (e^{-i})
// block = (bc,d), 256 threads
// ---------------------------------------------------------------------------
__global__ __launch_bounds__(256) void k_fwd_w(const float* __restrict__ x,
                                               float2* __restrict__ X1) {
  __shared__ float tile[64][65];
  __shared__ float2 tw[64];
  int t = threadIdx.x;
  if (t < 64) { float s, c; sincosf(TWO_PI_OVER_64 * t, &s, &c); tw[t] = make_float2(c, s); }
  const float* xr = x + (size_t)blockIdx.x * 4096;
  for (int i = t; i < 4096; i += 256) tile[i >> 6][i & 63] = xr[i];
  __syncthreads();
  float2* dst = X1 + (size_t)blockIdx.x * 512;
  for (int p = t; p < 512; p += 256) {
    int h = p >> 3, k = p & 7;
    float re = 0.f, im = 0.f;
    const float* row = tile[h];
#pragma unroll 8
    for (int w = 0; w < 64; ++w) {
      float2 cs = tw[(w * k) & 63];
      float v = row[w];
      re += v * cs.x;
      im -= v * cs.y;
    }
    dst[p] = make_float2(re, im);
  }
}

// ---------------------------------------------------------------------------
// Forward DFT along H: X1[bc,d,h,kw] -> X2[bc,d,kh,kw], kh in {0..7,56..63}
// block = (bc,d), 128 threads, one output each
// ---------------------------------------------------------------------------
__global__ __launch_bounds__(128) void k_fwd_h(const float2* __restrict__ X1,
                                               float2* __restrict__ X2) {
  __shared__ float2 tile[64][8];
  __shared__ float2 tw[64];
  int t = threadIdx.x;
  if (t < 64) { float s, c; sincosf(TWO_PI_OVER_64 * t, &s, &c); tw[t] = make_float2(c, s); }
  const float2* src = X1 + (size_t)blockIdx.x * 512;
  for (int i = t; i < 512; i += 128) tile[i >> 3][i & 7] = src[i];
  __syncthreads();
  int kh = t >> 3, k = t & 7;
  int f = (kh < 8) ? kh : kh + 48;
  float re = 0.f, im = 0.f;
#pragma unroll 8
  for (int h = 0; h < 64; ++h) {
    float2 cs = tw[(h * f) & 63];
    float2 v = tile[h][k];
    re += v.x * cs.x + v.y * cs.y;  // X * e^{-i t}
    im += v.y * cs.x - v.x * cs.y;
  }
  X2[(size_t)blockIdx.x * 128 + t] = make_float2(re, im);
}

// ---------------------------------------------------------------------------
// Forward DFT along D: X2[bc,d,kh,kw] -> X3[bc,kd,kh,kw]
// block = (bc,kh), 128 threads
// ---------------------------------------------------------------------------
__global__ __launch_bounds__(128) void k_fwd_d(const float2* __restrict__ X2,
                                               float2* __restrict__ X3) {
  __shared__ float2 tile[64][8];
  __shared__ float2 tw[64];
  int t = threadIdx.x;
  if (t < 64) { float s, c; sincosf(TWO_PI_OVER_64 * t, &s, &c); tw[t] = make_float2(c, s); }
  int kh = blockIdx.x & 15, bc = blockIdx.x >> 4;
  const float2* src = X2 + (size_t)bc * 8192 + kh * 8;
  for (int i = t; i < 512; i += 128) tile[i >> 3][i & 7] = src[(i >> 3) * 128 + (i & 7)];
  __syncthreads();
  int kd = t >> 3, k = t & 7;
  int f = (kd < 8) ? kd : kd + 48;
  float re = 0.f, im = 0.f;
#pragma unroll 8
  for (int d = 0; d < 64; ++d) {
    float2 cs = tw[(d * f) & 63];
    float2 v = tile[d][k];
    re += v.x * cs.x + v.y * cs.y;
    im += v.y * cs.x - v.x * cs.y;
  }
  X3[(size_t)bc * 2048 + kd * 128 + kh * 8 + k] = make_float2(re, im);
}

// ---------------------------------------------------------------------------
// Mode mixing: Y3[b,co,mode] = sum_ci X3[b,ci,mode] * (wr + i wi)[corner,ci,co,md,mh,kw]
// block = (kd,kh) : 256 blocks, thread = (co,kw)
// ---------------------------------------------------------------------------
__global__ __launch_bounds__(256) void k_mix(const float2* __restrict__ X3,
                                             const float* __restrict__ wr,
                                             const float* __restrict__ wi,
                                             float2* __restrict__ Y3) {
  __shared__ float2 xs[4][32][8];
  int t = threadIdx.x;
  int kd = blockIdx.x >> 4, kh = blockIdx.x & 15;
  for (int i = t; i < 1024; i += 256) {
    int b = i >> 8, ci = (i >> 3) & 31, k = i & 7;
    xs[b][ci][k] = X3[(size_t)(b * 32 + ci) * 2048 + kd * 128 + kh * 8 + k];
  }
  __syncthreads();
  int corner = ((kd >= 8) ? 2 : 0) + ((kh >= 8) ? 1 : 0);
  int md = kd & 7, mh = kh & 7;
  int co = t >> 3, k = t & 7;
  size_t wbase = (size_t)corner * 32 * 32 * 512 + (size_t)md * 64 + (size_t)mh * 8 + k;
  float ar0 = 0, ai0 = 0, ar1 = 0, ai1 = 0, ar2 = 0, ai2 = 0, ar3 = 0, ai3 = 0;
  for (int ci = 0; ci < 32; ++ci) {
    size_t o = wbase + (size_t)(ci * 32 + co) * 512;
    float wre = wr[o], wim = wi[o];
    float2 v0 = xs[0][ci][k], v1 = xs[1][ci][k];
    float2 v2 = xs[2][ci][k], v3 = xs[3][ci][k];
    ar0 += v0.x * wre - v0.y * wim;  ai0 += v0.x * wim + v0.y * wre;
    ar1 += v1.x * wre - v1.y * wim;  ai1 += v1.x * wim + v1.y * wre;
    ar2 += v2.x * wre - v2.y * wim;  ai2 += v2.x * wim + v2.y * wre;
    ar3 += v3.x * wre - v3.y * wim;  ai3 += v3.x * wim + v3.y * wre;
  }
  size_t obase = (size_t)kd * 128 + kh * 8 + k;
  Y3[(size_t)(0 * 32 + co) * 2048 + obase] = make_float2(ar0, ai0);
  Y3[(size_t)(1 * 32 + co) * 2048 + obase] = make_float2(ar1, ai1);
  Y3[(size_t)(2 * 32 + co) * 2048 + obase] = make_float2(ar2, ai2);
  Y3[(size_t)(3 * 32 + co) * 2048 + obase] = make_float2(ar3, ai3);
}

// ---------------------------------------------------------------------------
// Inverse DFT along D: Y3[bc,kd,kh,kw] -> Z1[bc,d,kh,kw] (e^{+i}, scale 1/64^3)
// block = (bc,kh), 128 threads, 4 outputs each
// ---------------------------------------------------------------------------
__global__ __launch_bounds__(128) void k_inv_d(const float2* __restrict__ Y3,
                                               float2* __restrict__ Z1) {
  __shared__ float2 tile[16][8];
  __shared__ float2 tw[64];
  int t = threadIdx.x;
  if (t < 64) { float s, c; sincosf(TWO_PI_OVER_64 * t, &s, &c); tw[t] = make_float2(c, s); }
  int kh = blockIdx.x & 15, bc = blockIdx.x >> 4;
  { int kd = t >> 3, k = t & 7;
    tile[kd][k] = Y3[(size_t)bc * 2048 + kd * 128 + kh * 8 + k]; }
  __syncthreads();
  int dbase = t >> 3, k = t & 7;
  const float sc = 1.f / 262144.f;
#pragma unroll
  for (int j = 0; j < 4; ++j) {
    int d = dbase + 16 * j;
    float re = 0.f, im = 0.f;
#pragma unroll
    for (int kd = 0; kd < 16; ++kd) {
      int f = (kd < 8) ? kd : kd + 48;
      float2 cs = tw[(d * f) & 63];
      float2 v = tile[kd][k];
      re += v.x * cs.x - v.y * cs.y;  // X * e^{+i t}
      im += v.x * cs.y + v.y * cs.x;
    }
    Z1[(size_t)bc * 8192 + d * 128 + kh * 8 + k] = make_float2(re * sc, im * sc);
  }
}

// ---------------------------------------------------------------------------
// Inverse DFT along H: Z1[bc,d,kh,kw] -> Z2[bc,d,h,kw]
// block = (bc,d), 128 threads, 4 outputs each
// ---------------------------------------------------------------------------
__global__ __launch_bounds__(128) void k_inv_h(const float2* __restrict__ Z1,
                                               float2* __restrict__ Z2) {
  __shared__ float2 tile[16][8];
  __shared__ float2 tw[64];
  int t = threadIdx.x;
  if (t < 64) { float s, c; sincosf(TWO_PI_OVER_64 * t, &s, &c); tw[t] = make_float2(c, s); }
  int d = blockIdx.x & 63, bc = blockIdx.x >> 6;
  { int kh = t >> 3, k = t & 7;
    tile[kh][k] = Z1[(size_t)bc * 8192 + d * 128 + kh * 8 + k]; }
  __syncthreads();
  int hbase = t >> 3, k = t & 7;
#pragma unroll
  for (int j = 0; j < 4; ++j) {
    int h = hbase + 16 * j;
    float re = 0.f, im = 0.f;
#pragma unroll
    for (int kh = 0; kh < 16; ++kh) {
      int f = (kh < 8) ? kh : kh + 48;
      float2 cs = tw[(h * f) & 63];
      float2 v = tile[kh][k];
      re += v.x * cs.x - v.y * cs.y;
      im += v.x * cs.y + v.y * cs.x;
    }
    Z2[(size_t)bc * 32768 + d * 512 + h * 8 + k] = make_float2(re, im);
  }
}

// ---------------------------------------------------------------------------
// Fused: irfft along W (8 modes) + skip linear + bias + GELU, in-place on x.
// block = (b,d,h) : 16384 blocks, 256 threads
// ---------------------------------------------------------------------------
__global__ __launch_bounds__(256) void k_inv_w_skip(const float2* __restrict__ Z2,
                                                    float* __restrict__ x,
                                                    const float* __restrict__ skw,
                                                    const float* __restrict__ skb) {
  __shared__ float xt[32][64];
  __shared__ float ot[32][65];
  __shared__ float2 zt[32][9];
  __shared__ float sw[32][32];
  __shared__ float sb[32];
  __shared__ float2 tw[64];
  int t = threadIdx.x;
  if (t < 64) { float s, c; sincosf(TWO_PI_OVER_64 * t, &s, &c); tw[t] = make_float2(c, s); }
  int b = blockIdx.x >> 12, d = (blockIdx.x >> 6) & 63, h = blockIdx.x & 63;
  size_t xbase = (size_t)b * 32 * NSP + (size_t)d * 4096 + (size_t)h * 64;
  for (int i = t; i < 2048; i += 256) {
    int ci = i >> 6, w = i & 63;
    xt[ci][w] = x[xbase + (size_t)ci * NSP + w];
  }
  { int co = t >> 3, k = t & 7;
    zt[co][k] = Z2[(size_t)(b * 32 + co) * 32768 + (size_t)d * 512 + h * 8 + k]; }
  for (int i = t; i < 1024; i += 256) sw[i >> 5][i & 31] = skw[i];
  if (t < 32) sb[t] = skb[t];
  __syncthreads();

  int co = t >> 3, w0 = t & 7;
  float acc[8];
#pragma unroll
  for (int j = 0; j < 8; ++j) {
    int w = w0 + 8 * j;
    float y = zt[co][0].x;  // c2r: imag of DC bin ignored
#pragma unroll
    for (int k = 1; k < 8; ++k) {
      float2 cs = tw[(k * w) & 63];
      y += 2.f * (zt[co][k].x * cs.x - zt[co][k].y * cs.y);
    }
    acc[j] = y + sb[co];
  }
  for (int ci = 0; ci < 32; ++ci) {
    float wv = sw[ci][co];
#pragma unroll
    for (int j = 0; j < 8; ++j) acc[j] += xt[ci][w0 + 8 * j] * wv;
  }
#pragma unroll
  for (int j = 0; j < 8; ++j) {
    float g = acc[j];
    float u = 0.7978845608028654f * (g + 0.044715f * g * g * g);
    ot[co][w0 + 8 * j] = 0.5f * g * (1.f + tanhf(u));
  }
  __syncthreads();
  for (int i = t; i < 2048; i += 256) {
    int ci = i >> 6, w = i & 63;
    x[xbase + (size_t)ci * NSP + w] = ot[ci][w];
  }
}

// ---------------------------------------------------------------------------
// Spatial partial sums: pr[bc*4+q] = sum of x[bc, q-th quarter]
// ---------------------------------------------------------------------------
__global__ __launch_bounds__(256) void k_mean(const float* __restrict__ x,
                                              float* __restrict__ pr) {
  __shared__ float red[256];
  int t = threadIdx.x;
  int bc = blockIdx.x >> 2, q = blockIdx.x & 3;
  const float* xr = x + (size_t)bc * NSP + (size_t)q * 65536;
  float s = 0.f;
  for (int i = t; i < 65536; i += 256) s += xr[i];
  red[t] = s;
  __syncthreads();
  for (int o = 128; o > 0; o >>= 1) {
    if (t < o) red[t] += red[t + o];
    __syncthreads();
  }
  if (t == 0) pr[blockIdx.x] = red[0];
}

// ---------------------------------------------------------------------------
// Head: collapsed layer-4 (DC-only spectral + skip) + proj + MLP -> out[4,3]
// ---------------------------------------------------------------------------
__global__ __launch_bounds__(128) void k_head(const float* __restrict__ pr,
                                              const float* __restrict__ swr,
                                              const float* __restrict__ skw,
                                              const float* __restrict__ skb,
                                              const float* __restrict__ pw,
                                              const float* __restrict__ pb,
                                              const float* __restrict__ f1w,
                                              const float* __restrict__ f1b,
                                              const float* __restrict__ f2w,
                                              const float* __restrict__ f2b,
                                              const float* __restrict__ f3w,
                                              const float* __restrict__ f3b,
                                              float* __restrict__ out) {
  __shared__ float m[128], h1[128], p2[128], f1[512], f2[256];
  int t = threadIdx.x;
  m[t] = (pr[4 * t] + pr[4 * t + 1] + pr[4 * t + 2] + pr[4 * t + 3]) * (1.f / 262144.f);
  __syncthreads();
  {  // layer 3 collapsed: mean(y3+s3) = m @ (wr_dc + skip_w3) + skip_b3
    int b = t >> 5, co = t & 31;
    float acc = skb[96 + co];
    for (int ci = 0; ci < 32; ++ci) {
      float wdc = swr[((size_t)12 * 1024 + (size_t)(ci * 32 + co)) * 512];
      acc += m[b * 32 + ci] * (wdc + skw[3072 + ci * 32 + co]);
    }
    h1[t] = acc;
  }
  __syncthreads();
  {  // proj
    int b = t >> 5, o = t & 31;
    float acc = pb[o];
    for (int c = 0; c < 32; ++c) acc += h1[b * 32 + c] * pw[c * 32 + o];
    p2[t] = acc;
  }
  __syncthreads();
  for (int j = 0; j < 4; ++j) {  // fc1 + relu
    int idx = t + 128 * j;
    int b = idx >> 7, o = idx & 127;
    float acc = f1b[o];
    for (int c = 0; c < 32; ++c) acc += p2[b * 32 + c] * f1w[c * 128 + o];
    f1[idx] = fmaxf(acc, 0.f);
  }
  __syncthreads();
  for (int j = 0; j < 2; ++j) {  // fc2 + relu
    int idx = t + 128 * j;
    int b = idx >> 6, o = idx & 63;
    float acc = f2b[o];
    for (int c = 0; c < 128; ++c) acc += f1[b * 128 + c] * f2w[c * 64 + o];
    f2[idx] = fmaxf(acc, 0.f);
  }
  __syncthreads();
  if (t < 12) {  // fc3
    int b = t / 3, o = t % 3;
    float acc = f3b[o];
    for (int c = 0; c < 64; ++c) acc += f2[b * 64 + c] * f3w[c * 3 + o];
    out[t] = acc;
  }
}

// ---------------------------------------------------------------------------
extern "C" void kernel_launch(void* const* d_in, const int* in_sizes, int n_in,
                              void* d_out, int out_size, void* d_ws, size_t ws_size,
                              hipStream_t stream) {
  const float* vel = (const float*)d_in[0];
  const float* ptt = (const float*)d_in[1];
  const float* lw  = (const float*)d_in[2];
  const float* lb  = (const float*)d_in[3];
  const float* swr = (const float*)d_in[4];
  const float* swi = (const float*)d_in[5];
  const float* skw = (const float*)d_in[6];
  const float* skb = (const float*)d_in[7];
  const float* pw  = (const float*)d_in[8];
  const float* pb  = (const float*)d_in[9];
  const float* f1w = (const float*)d_in[10];
  const float* f1b = (const float*)d_in[11];
  const float* f2w = (const float*)d_in[12];
  const float* f2b = (const float*)d_in[13];
  const float* f3w = (const float*)d_in[14];
  const float* f3b = (const float*)d_in[15];
  float* out = (float*)d_out;

  // Workspace layout (bytes):
  //   x   : 134,217,728   (B*32*64^3 fp32, in-place across layers)
  //   X1  :  33,554,432   (also Z2)
  //   X2  :   8,388,608   (also Z1)
  //   X3  :   2,097,152
  //   Y3  :   2,097,152
  //   pr  :       2,048
  char* ws = (char*)d_ws;
  float*  x  = (float*)(ws);
  float2* X1 = (float2*)(ws + 134217728ULL);
  float2* X2 = (float2*)(ws + 167772160ULL);
  float2* X3 = (float2*)(ws + 176160768ULL);
  float2* Y3 = (float2*)(ws + 178257920ULL);
  float*  pr = (float*)(ws + 180355072ULL);
  if (ws_size < 180357120ULL) return;  // insufficient scratch — bail

  k_lift<<<4096, 256, 0, stream>>>(vel, ptt, lw, lb, x);
  for (int l = 0; l < 3; ++l) {
    k_fwd_w<<<8192, 256, 0, stream>>>(x, X1);
    k_fwd_h<<<8192, 128, 0, stream>>>(X1, X2);
    k_fwd_d<<<2048, 128, 0, stream>>>(X2, X3);
    k_mix<<<256, 256, 0, stream>>>(X3, swr + (size_t)l * 2097152,
                                   swi + (size_t)l * 2097152, Y3);
    k_inv_d<<<2048, 128, 0, stream>>>(Y3, X2);   // Z1 into X2 buffer
    k_inv_h<<<8192, 128, 0, stream>>>(X2, X1);   // Z2 into X1 buffer
    k_inv_w_skip<<<16384, 256, 0, stream>>>(X1, x, skw + (size_t)l * 1024,
                                            skb + (size_t)l * 32);
  }
  k_mean<<<512, 256, 0, stream>>>(x, pr);
  k_head<<<1, 128, 0, stream>>>(pr, swr, skw, skb, pw, pb, f1w, f1b,
                                f2w, f2b, f3w, f3b, out);
}

// Round 2
// 724.180 us; speedup vs baseline: 2.4175x; 2.4175x over previous
//
#include <hip/hip_runtime.h>
#include <math.h>

#define NSP 262144  // 64^3
static constexpr float TWO_PI_OVER_64 = 0.09817477042468103f;

// ===========================================================================
// Layer-0 front end: DFT (W then H) of the 2 raw input channels.
// grid = (b,ch,d) = 512 blocks, 256 threads.
// VP2[(b*2+ch)*64+d][kh*8+kw]  (float2), kh in {0..7 | 56..63 -> idx 8..15}
// ===========================================================================
__global__ __launch_bounds__(256) void k_fwd_wh2(const float* __restrict__ vel,
                                                 const float* __restrict__ ptt,
                                                 float2* __restrict__ VP2) {
  __shared__ float plane[64][65];
  __shared__ float2 A[64][8];
  __shared__ float2 tw[64];
  int t = threadIdx.x;
  if (t < 64) { float s, c; sincosf(TWO_PI_OVER_64 * t, &s, &c); tw[t] = make_float2(c, s); }
  int b = blockIdx.x >> 7, ch = (blockIdx.x >> 6) & 1, d = blockIdx.x & 63;
  const float4* src = (const float4*)((ch ? ptt : vel) + (size_t)b * NSP + d * 4096);
  for (int p = 0; p < 4; ++p) {
    int i = t + 256 * p;
    float4 v = src[i];
    int h = i >> 4, sg = (i & 15) * 4;
    plane[h][sg] = v.x; plane[h][sg + 1] = v.y; plane[h][sg + 2] = v.z; plane[h][sg + 3] = v.w;
  }
  __syncthreads();
  for (int p = 0; p < 2; ++p) {
    int o = t + 256 * p;
    int h = o >> 3, kw = o & 7;
    float re = 0.f, im = 0.f;
    for (int w = 0; w < 64; ++w) {
      float2 cs = tw[(kw * w) & 63];
      float v = plane[h][w];
      re += v * cs.x; im -= v * cs.y;
    }
    A[h][kw] = make_float2(re, im);
  }
  __syncthreads();
  if (t < 128) {
    int kh = t >> 3, kw = t & 7;
    int f = (kh < 8) ? kh : kh + 48;
    float re = 0.f, im = 0.f;
    for (int h = 0; h < 64; ++h) {
      float2 cs = tw[(h * f) & 63];
      float2 a = A[h][kw];
      re += a.x * cs.x + a.y * cs.y;
      im += a.y * cs.x - a.x * cs.y;
    }
    VP2[(size_t)blockIdx.x * 128 + t] = make_float2(re, im);
  }
}

// ===========================================================================
// Layer-0: DFT along D of the 2 channels + fold lift -> X3[b,ci,kd,kh,kw]
// grid = (b,kh) = 64 blocks, 256 threads.
// ===========================================================================
__global__ __launch_bounds__(256) void k_fwd_d_lift(const float2* __restrict__ VP2,
                                                    const float* __restrict__ lw,
                                                    const float* __restrict__ lb,
                                                    float2* __restrict__ X3) {
  __shared__ float2 tile[2][64][8];
  __shared__ float2 F[2][16][8];
  __shared__ float2 tw[64];
  int t = threadIdx.x;
  if (t < 64) { float s, c; sincosf(TWO_PI_OVER_64 * t, &s, &c); tw[t] = make_float2(c, s); }
  int b = blockIdx.x >> 4, kh = blockIdx.x & 15;
  for (int p = 0; p < 4; ++p) {
    int i = t + 256 * p;
    int ch = i >> 9, dd = (i >> 3) & 63, kw = i & 7;
    tile[ch][dd][kw] = VP2[(size_t)((b * 2 + ch) * 64 + dd) * 128 + kh * 8 + kw];
  }
  __syncthreads();
  { int ch = t >> 7, kd = (t >> 3) & 15, kw = t & 7;
    int f = (kd < 8) ? kd : kd + 48;
    float re = 0.f, im = 0.f;
    for (int dd = 0; dd < 64; ++dd) {
      float2 cs = tw[(dd * f) & 63];
      float2 v = tile[ch][dd][kw];
      re += v.x * cs.x + v.y * cs.y;
      im += v.y * cs.x - v.x * cs.y;
    }
    F[ch][kd][kw] = make_float2(re, im); }
  __syncthreads();
  for (int p = 0; p < 16; ++p) {
    int o = t + 256 * p;  // 4096 outputs
    int ci = o >> 7, kd = (o >> 3) & 15, kw = o & 7;
    float2 f0 = F[0][kd][kw], f1 = F[1][kd][kw];
    float w0 = lw[ci], w1 = lw[32 + ci];
    float2 v = make_float2(w0 * f0.x + w1 * f1.x, w0 * f0.y + w1 * f1.y);
    if (kh == 0 && kd == 0 && kw == 0) v.x += lb[ci] * 262144.f;
    X3[(size_t)(b * 32 + ci) * 2048 + kd * 128 + kh * 8 + kw] = v;
  }
}

// ===========================================================================
// Forward DFT along H (layers 1,2): X1 -> X2
// ===========================================================================
__global__ __launch_bounds__(128) void k_fwd_h(const float2* __restrict__ X1,
                                               float2* __restrict__ X2) {
  __shared__ float2 tile[64][8];
  __shared__ float2 tw[64];
  int t = threadIdx.x;
  if (t < 64) { float s, c; sincosf(TWO_PI_OVER_64 * t, &s, &c); tw[t] = make_float2(c, s); }
  const float4* s4 = (const float4*)(X1 + (size_t)blockIdx.x * 512);
  float4* t4 = (float4*)tile;
  t4[t] = s4[t];
  t4[t + 128] = s4[t + 128];
  __syncthreads();
  int kh = t >> 3, k = t & 7;
  int f = (kh < 8) ? kh : kh + 48;
  float re = 0.f, im = 0.f;
#pragma unroll 8
  for (int h = 0; h < 64; ++h) {
    float2 cs = tw[(h * f) & 63];
    float2 v = tile[h][k];
    re += v.x * cs.x + v.y * cs.y;
    im += v.y * cs.x - v.x * cs.y;
  }
  X2[(size_t)blockIdx.x * 128 + t] = make_float2(re, im);
}

// ===========================================================================
// Forward DFT along D (layers 1,2): X2 -> X3
// ===========================================================================
__global__ __launch_bounds__(128) void k_fwd_d(const float2* __restrict__ X2,
                                               float2* __restrict__ X3) {
  __shared__ float2 tile[64][8];
  __shared__ float2 tw[64];
  int t = threadIdx.x;
  if (t < 64) { float s, c; sincosf(TWO_PI_OVER_64 * t, &s, &c); tw[t] = make_float2(c, s); }
  int kh = blockIdx.x & 15, bc = blockIdx.x >> 4;
  const float2* src = X2 + (size_t)bc * 8192 + kh * 8;
  for (int i = t; i < 512; i += 128) tile[i >> 3][i & 7] = src[(i >> 3) * 128 + (i & 7)];
  __syncthreads();
  int kd = t >> 3, k = t & 7;
  int f = (kd < 8) ? kd : kd + 48;
  float re = 0.f, im = 0.f;
#pragma unroll 8
  for (int d = 0; d < 64; ++d) {
    float2 cs = tw[(d * f) & 63];
    float2 v = tile[d][k];
    re += v.x * cs.x + v.y * cs.y;
    im += v.y * cs.x - v.x * cs.y;
  }
  X3[(size_t)bc * 2048 + kd * 128 + kh * 8 + k] = make_float2(re, im);
}

// ===========================================================================
// Mode mixing (unchanged from R1)
// ===========================================================================
__global__ __launch_bounds__(256) void k_mix(const float2* __restrict__ X3,
                                             const float* __restrict__ wr,
                                             const float* __restrict__ wi,
                                             float2* __restrict__ Y3) {
  __shared__ float2 xs[4][32][8];
  int t = threadIdx.x;
  int kd = blockIdx.x >> 4, kh = blockIdx.x & 15;
  for (int i = t; i < 1024; i += 256) {
    int b = i >> 8, ci = (i >> 3) & 31, k = i & 7;
    xs[b][ci][k] = X3[(size_t)(b * 32 + ci) * 2048 + kd * 128 + kh * 8 + k];
  }
  __syncthreads();
  int corner = ((kd >= 8) ? 2 : 0) + ((kh >= 8) ? 1 : 0);
  int md = kd & 7, mh = kh & 7;
  int co = t >> 3, k = t & 7;
  size_t wbase = (size_t)corner * 32 * 32 * 512 + (size_t)md * 64 + (size_t)mh * 8 + k;
  float ar0 = 0, ai0 = 0, ar1 = 0, ai1 = 0, ar2 = 0, ai2 = 0, ar3 = 0, ai3 = 0;
  for (int ci = 0; ci < 32; ++ci) {
    size_t o = wbase + (size_t)(ci * 32 + co) * 512;
    float wre = wr[o], wim = wi[o];
    float2 v0 = xs[0][ci][k], v1 = xs[1][ci][k];
    float2 v2 = xs[2][ci][k], v3 = xs[3][ci][k];
    ar0 += v0.x * wre - v0.y * wim;  ai0 += v0.x * wim + v0.y * wre;
    ar1 += v1.x * wre - v1.y * wim;  ai1 += v1.x * wim + v1.y * wre;
    ar2 += v2.x * wre - v2.y * wim;  ai2 += v2.x * wim + v2.y * wre;
    ar3 += v3.x * wre - v3.y * wim;  ai3 += v3.x * wim + v3.y * wre;
  }
  size_t obase = (size_t)kd * 128 + kh * 8 + k;
  Y3[(size_t)(0 * 32 + co) * 2048 + obase] = make_float2(ar0, ai0);
  Y3[(size_t)(1 * 32 + co) * 2048 + obase] = make_float2(ar1, ai1);
  Y3[(size_t)(2 * 32 + co) * 2048 + obase] = make_float2(ar2, ai2);
  Y3[(size_t)(3 * 32 + co) * 2048 + obase] = make_float2(ar3, ai3);
}

// ===========================================================================
// Fused inverse DFT along D then H: Y3 -> Z2 (into S buffer)
// grid = (bc, d-tile of 4) = 2048 blocks, 256 threads. Y3 is 2.1 MB -> L2-hot.
// ===========================================================================
__global__ __launch_bounds__(256) void k_inv_dh(const float2* __restrict__ Y3,
                                                float2* __restrict__ Z2) {
  __shared__ float2 yt[2048];      // [kd][kh][kw]
  __shared__ float2 zd[4][16][8];  // [dd][kh][kw]
  __shared__ float2 tw[64];
  int t = threadIdx.x;
  if (t < 64) { float s, c; sincosf(TWO_PI_OVER_64 * t, &s, &c); tw[t] = make_float2(c, s); }
  int bc = blockIdx.x >> 4, d0 = (blockIdx.x & 15) * 4;
  const float4* y4 = (const float4*)(Y3 + (size_t)bc * 2048);
  float4* yt4 = (float4*)yt;
  for (int p = 0; p < 4; ++p) yt4[t + 256 * p] = y4[t + 256 * p];
  __syncthreads();
  const float sc = 1.f / 262144.f;
  for (int p = 0; p < 2; ++p) {
    int o = t + 256 * p;
    int dd = o >> 7, kh = (o >> 3) & 15, kw = o & 7;
    int d = d0 + dd;
    float re = 0.f, im = 0.f;
#pragma unroll
    for (int kd = 0; kd < 16; ++kd) {
      int f = (kd < 8) ? kd : kd + 48;
      float2 cs = tw[(d * f) & 63];
      float2 v = yt[kd * 128 + kh * 8 + kw];
      re += v.x * cs.x - v.y * cs.y;
      im += v.x * cs.y + v.y * cs.x;
    }
    zd[dd][kh][kw] = make_float2(re * sc, im * sc);
  }
  __syncthreads();
  for (int p = 0; p < 8; ++p) {
    int o = t + 256 * p;
    int dd = o >> 9, h = (o >> 3) & 63, kw = o & 7;
    float re = 0.f, im = 0.f;
#pragma unroll
    for (int kh = 0; kh < 16; ++kh) {
      int f = (kh < 8) ? kh : kh + 48;
      float2 cs = tw[(h * f) & 63];
      float2 v = zd[dd][kh][kw];
      re += v.x * cs.x - v.y * cs.y;
      im += v.x * cs.y + v.y * cs.x;
    }
    Z2[((size_t)bc * 64 + d0 + dd) * 512 + h * 8 + kw] = make_float2(re, im);
  }
}

// ===========================================================================
// Fused tail: irfft-W + skip + gelu (+ write x & fwd-W of next layer, or mean).
// MODE 0: inputs = vel/ptt with folded lift+skip; writes x, X1 (in-place in S)
// MODE 1: inputs = x;                             writes x, X1 (in-place in S)
// MODE 2: inputs = x;                             channel-sum -> pr (atomics)
// grid = (b, d, h/2) = 8192 blocks, 256 threads = (co:32, wseg:8)
// ===========================================================================
template <int MODE>
__global__ __launch_bounds__(256, 3) void k_tail(
    const float2* __restrict__ S, const float* __restrict__ xin,
    const float* __restrict__ pttin, const float* __restrict__ lw,
    const float* __restrict__ lb, const float* __restrict__ skw,
    const float* __restrict__ skb, float* __restrict__ xout,
    float2* __restrict__ X1out, float* __restrict__ pr) {
  __shared__ float2 tw[64];
  __shared__ float2 zt[32][2][9];
  __shared__ float sw[32][32];  // MODE0: rows 0,1 = folded lift@skip; row 2 = folded bias
  __shared__ float xt[(MODE == 0) ? 2 : 32][2][64];
  __shared__ float gt[(MODE == 2) ? 1 : 32][2][68];
  int t = threadIdx.x;
  if (t < 64) { float s, c; sincosf(TWO_PI_OVER_64 * t, &s, &c); tw[t] = make_float2(c, s); }
  int b = blockIdx.x >> 11, d = (blockIdx.x >> 5) & 63, h0 = (blockIdx.x & 31) * 2;
  {  // Z2 tile
    int co = t >> 3, hh = (t >> 2) & 1, q = t & 3;
    const float4* S4 = (const float4*)S;
    float4 v = S4[(size_t)((b * 32 + co) * 64 + d) * 256 + (h0 + hh) * 4 + q];
    zt[co][hh][2 * q] = make_float2(v.x, v.y);
    zt[co][hh][2 * q + 1] = make_float2(v.z, v.w);
  }
  if constexpr (MODE == 0) {
    if (t < 64) {
      int ch = t >> 5, hh = (t >> 4) & 1, sg = t & 15;
      const float4* src = (const float4*)(ch ? pttin : xin);
      *(float4*)&xt[ch][hh][sg * 4] =
          src[((size_t)b * NSP + d * 4096 + (h0 + hh) * 64) / 4 + sg];
    } else if (t >= 128 && t < 192) {
      int j = (t >> 5) & 1, co = t & 31;
      float a = 0.f;
      for (int ci = 0; ci < 32; ++ci) a += lw[j * 32 + ci] * skw[ci * 32 + co];
      sw[j][co] = a;
    } else if (t >= 192 && t < 224) {
      int co = t & 31;
      float a = skb[co];
      for (int ci = 0; ci < 32; ++ci) a += lb[ci] * skw[ci * 32 + co];
      sw[2][co] = a;
    }
  } else {
    { int ci = t >> 3, q = t & 7;
      *(float4*)&sw[ci][q * 4] = ((const float4*)skw)[t]; }
    for (int p = 0; p < 4; ++p) {
      int idx = t + 256 * p, row = idx >> 4, ci = row >> 1, hh = row & 1, sg = idx & 15;
      *(float4*)&xt[ci][hh][sg * 4] =
          ((const float4*)xin)[(size_t)(((b * 32 + ci) * 64 + d) * 64 + h0 + hh) * 16 + sg];
    }
  }
  __syncthreads();

  int co = t >> 3, ws = t & 7;
  float bias = (MODE == 0) ? sw[2][co] : skb[co];
  float acc[2][8];
#pragma unroll
  for (int hh = 0; hh < 2; ++hh) {
    float z0 = zt[co][hh][0].x;
#pragma unroll
    for (int j = 0; j < 8; ++j) acc[hh][j] = bias + z0;
  }
#pragma unroll
  for (int k = 1; k < 8; ++k) {
    float2 z0 = zt[co][0][k], z1 = zt[co][1][k];
#pragma unroll
    for (int j = 0; j < 8; ++j) {
      float2 cs = tw[(k * (8 * ws + j)) & 63];
      acc[0][j] += 2.f * (z0.x * cs.x - z0.y * cs.y);
      acc[1][j] += 2.f * (z1.x * cs.x - z1.y * cs.y);
    }
  }
  constexpr int NCI = (MODE == 0) ? 2 : 32;
  for (int ci = 0; ci < NCI; ++ci) {
    float s = sw[ci][co];
#pragma unroll
    for (int hh = 0; hh < 2; ++hh) {
      float4 a = *(const float4*)&xt[ci][hh][8 * ws];
      float4 c2 = *(const float4*)&xt[ci][hh][8 * ws + 4];
      acc[hh][0] += a.x * s;  acc[hh][1] += a.y * s;
      acc[hh][2] += a.z * s;  acc[hh][3] += a.w * s;
      acc[hh][4] += c2.x * s; acc[hh][5] += c2.y * s;
      acc[hh][6] += c2.z * s; acc[hh][7] += c2.w * s;
    }
  }
#pragma unroll
  for (int hh = 0; hh < 2; ++hh)
#pragma unroll
    for (int j = 0; j < 8; ++j) {
      float g = acc[hh][j];
      float u = 0.7978845608028654f * (g + 0.044715f * g * g * g);
      acc[hh][j] = __fdividef(g, 1.f + __expf(-2.f * u));  // g*sigmoid(2u) == gelu(tanh)
    }

  if constexpr (MODE == 2) {
    float s = 0.f;
#pragma unroll
    for (int hh = 0; hh < 2; ++hh)
#pragma unroll
      for (int j = 0; j < 8; ++j) s += acc[hh][j];
    s += __shfl_down(s, 4, 8);
    s += __shfl_down(s, 2, 8);
    s += __shfl_down(s, 1, 8);
    if (ws == 0) atomicAdd(&pr[b * 32 + co], s);
  } else {
#pragma unroll
    for (int hh = 0; hh < 2; ++hh) {
      *(float4*)&gt[co][hh][8 * ws] = make_float4(acc[hh][0], acc[hh][1], acc[hh][2], acc[hh][3]);
      *(float4*)&gt[co][hh][8 * ws + 4] = make_float4(acc[hh][4], acc[hh][5], acc[hh][6], acc[hh][7]);
    }
    __syncthreads();
    for (int p = 0; p < 4; ++p) {  // write x_{l+1}
      int idx = t + 256 * p, row = idx >> 4, ci = row >> 1, hh = row & 1, sg = idx & 15;
      ((float4*)xout)[(size_t)(((b * 32 + ci) * 64 + d) * 64 + h0 + hh) * 16 + sg] =
          *(float4*)&gt[ci][hh][sg * 4];
    }
    for (int p = 0; p < 2; ++p) {  // fused fwd-W of next layer, in-place over Z2
      int o = t + 256 * p;
      int c2 = o >> 4, hh = (o >> 3) & 1, kw = o & 7;
      float re = 0.f, im = 0.f;
      for (int w = 0; w < 64; ++w) {
        float g = gt[c2][hh][w];
        float2 cs = tw[(kw * w) & 63];
        re += g * cs.x;
        im -= g * cs.y;
      }
      X1out[(size_t)((b * 32 + c2) * 64 + d) * 512 + (h0 + hh) * 8 + kw] = make_float2(re, im);
    }
  }
}

// ===========================================================================
// Head (unchanged except pr is now direct per-(b,co) sums)
// ===========================================================================
__global__ __launch_bounds__(128) void k_head(const float* __restrict__ pr,
                                              const float* __restrict__ swr,
                                              const float* __restrict__ skw,
                                              const float* __restrict__ skb,
                                              const float* __restrict__ pw,
                                              const float* __restrict__ pb,
                                              const float* __restrict__ f1w,
                                              const float* __restrict__ f1b,
                                              const float* __restrict__ f2w,
                                              const float* __restrict__ f2b,
                                              const float* __restrict__ f3w,
                                              const float* __restrict__ f3b,
                                              float* __restrict__ out) {
  __shared__ float m[128], h1[128], p2[128], f1[512], f2[256];
  int t = threadIdx.x;
  m[t] = pr[t] * (1.f / 262144.f);
  __syncthreads();
  { int b = t >> 5, co = t & 31;
    float acc = skb[96 + co];
    for (int ci = 0; ci < 32; ++ci) {
      float wdc = swr[((size_t)12 * 1024 + (size_t)(ci * 32 + co)) * 512];
      acc += m[b * 32 + ci] * (wdc + skw[3072 + ci * 32 + co]);
    }
    h1[t] = acc; }
  __syncthreads();
  { int b = t >> 5, o = t & 31;
    float acc = pb[o];
    for (int c = 0; c < 32; ++c) acc += h1[b * 32 + c] * pw[c * 32 + o];
    p2[t] = acc; }
  __syncthreads();
  for (int j = 0; j < 4; ++j) {
    int idx = t + 128 * j, b = idx >> 7, o = idx & 127;
    float acc = f1b[o];
    for (int c = 0; c < 32; ++c) acc += p2[b * 32 + c] * f1w[c * 128 + o];
    f1[idx] = fmaxf(acc, 0.f);
  }
  __syncthreads();
  for (int j = 0; j < 2; ++j) {
    int idx = t + 128 * j, b = idx >> 6, o = idx & 63;
    float acc = f2b[o];
    for (int c = 0; c < 128; ++c) acc += f1[b * 128 + c] * f2w[c * 64 + o];
    f2[idx] = fmaxf(acc, 0.f);
  }
  __syncthreads();
  if (t < 12) {
    int b = t / 3, o = t % 3;
    float acc = f3b[o];
    for (int c = 0; c < 64; ++c) acc += f2[b * 64 + c] * f3w[c * 3 + o];
    out[t] = acc;
  }
}

// ===========================================================================
extern "C" void kernel_launch(void* const* d_in, const int* in_sizes, int n_in,
                              void* d_out, int out_size, void* d_ws, size_t ws_size,
                              hipStream_t stream) {
  const float* vel = (const float*)d_in[0];
  const float* ptt = (const float*)d_in[1];
  const float* lw  = (const float*)d_in[2];
  const float* lb  = (const float*)d_in[3];
  const float* swr = (const float*)d_in[4];
  const float* swi = (const float*)d_in[5];
  const float* skw = (const float*)d_in[6];
  const float* skb = (const float*)d_in[7];
  const float* pw  = (const float*)d_in[8];
  const float* pb  = (const float*)d_in[9];
  const float* f1w = (const float*)d_in[10];
  const float* f1b = (const float*)d_in[11];
  const float* f2w = (const float*)d_in[12];
  const float* f2b = (const float*)d_in[13];
  const float* f3w = (const float*)d_in[14];
  const float* f3b = (const float*)d_in[15];
  float* out = (float*)d_out;

  // Workspace: x 134MB | S (Z2/X1 shared) 33.5MB | X2/VP2 8.4MB | X3 2.1MB
  //            Y3 2.1MB | pr 512B   (total 180,355,584 B)
  char* ws = (char*)d_ws;
  float*  x   = (float*)(ws);
  float2* S   = (float2*)(ws + 134217728ULL);
  float2* X2  = (float2*)(ws + 167772160ULL);
  float2* VP2 = X2;  // alias: VP2 only used before X2
  float2* X3  = (float2*)(ws + 176160768ULL);
  float2* Y3  = (float2*)(ws + 178257920ULL);
  float*  pr  = (float*)(ws + 180355072ULL);
  if (ws_size < 180355584ULL) return;

  hipMemsetAsync(pr, 0, 512, stream);

  // ---- layer 0 (lift folded into the 2-channel spectral path) ----
  k_fwd_wh2<<<512, 256, 0, stream>>>(vel, ptt, VP2);
  k_fwd_d_lift<<<64, 256, 0, stream>>>(VP2, lw, lb, X3);
  k_mix<<<256, 256, 0, stream>>>(X3, swr, swi, Y3);
  k_inv_dh<<<2048, 256, 0, stream>>>(Y3, S);
  k_tail<0><<<8192, 256, 0, stream>>>(S, vel, ptt, lw, lb, skw, skb, x, S, nullptr);

  // ---- layer 1 ----
  k_fwd_h<<<8192, 128, 0, stream>>>(S, X2);
  k_fwd_d<<<2048, 128, 0, stream>>>(X2, X3);
  k_mix<<<256, 256, 0, stream>>>(X3, swr + 2097152, swi + 2097152, Y3);
  k_inv_dh<<<2048, 256, 0, stream>>>(Y3, S);
  k_tail<1><<<8192, 256, 0, stream>>>(S, x, nullptr, nullptr, nullptr,
                                      skw + 1024, skb + 32, x, S, nullptr);

  // ---- layer 2 (mean fused, no x/X1 writeback) ----
  k_fwd_h<<<8192, 128, 0, stream>>>(S, X2);
  k_fwd_d<<<2048, 128, 0, stream>>>(X2, X3);
  k_mix<<<256, 256, 0, stream>>>(X3, swr + 2 * 2097152, swi + 2 * 2097152, Y3);
  k_inv_dh<<<2048, 256, 0, stream>>>(Y3, S);
  k_tail<2><<<8192, 256, 0, stream>>>(S, x, nullptr, nullptr, nullptr,
                                      skw + 2048, skb + 64, nullptr, nullptr, pr);

  // ---- collapsed layer 3 + proj + MLP head ----
  k_head<<<1, 128, 0, stream>>>(pr, swr, skw, skb, pw, pb, f1w, f1b,
                                f2w, f2b, f3w, f3b, out);
}